// Round 7
// baseline (52.789 us; speedup 1.0000x reference)
//
#include <hip/hip_runtime.h>
#include <hip/hip_bf16.h>

// LogicConv3d: B=64, C=32, H=32, W=32, K=64, P=784, S=16 gathers/side.
// R7: batch-transposed gathers. x_t[o][b] (8 MB) makes each site-gather a
// coalesced 256-B global load (lane=b), eliminating R5/R6's LDS bank
// conflicts and the 128KB/CU staging bubble. Site index is wave-uniform ->
// offs/coefs ride the SMEM (s_load) pipe; offs traffic drops 64x.
// Output coalesced via padded LDS transpose tile. Tree in 3-fma form.

#define B_  64
#define C_  32
#define H_  32
#define W_  32
#define K_  64
#define P_  784
#define CHW (C_*H_*W_)      // 32768
#define HW  (H_*W_)         // 1024
#define SITES (K_*P_)       // 50176
#define NPACKBLK (SITES / 256)              // 196 (exact)
#define NTRANBLK (CHW / 64)                 // 512 tiles of 64 o
#define NCOEFBLK ((K_ * 31 + 255) / 256)    // 8

__constant__ float COEF_[16][4] = {
    {0, 0, 0, 0}, {0, 0, 0, 1}, {0, 1, 0, -1}, {0, 1, 0, 0},
    {0, 0, 1, -1}, {0, 0, 1, 0}, {0, 1, 1, -2}, {0, 1, 1, -1},
    {1, -1, -1, 1}, {1, -1, -1, 2}, {1, 0, -1, 0}, {1, 0, -1, 1},
    {1, -1, 0, 0}, {1, -1, 0, 1}, {1, 0, 0, -1}, {1, 0, 0, 0}
};

// ---- kernel 1: fused prep = pack offs (0..195) | transpose x (196..707) | coefs (708..715) ----
__global__ __launch_bounds__(256) void prep_kernel(
    const float* __restrict__ x,
    const int* __restrict__ a_idx, const int* __restrict__ b_idx,
    const float* __restrict__ w0, const float* __restrict__ w1,
    const float* __restrict__ w2, const float* __restrict__ w3,
    const float* __restrict__ w4,
    float* __restrict__ xt,          // [CHW][64]
    unsigned* __restrict__ offs,     // [SITES][32] element offsets (o*64)
    float4* __restrict__ cws)        // [K_*31]
{
    const int bid = blockIdx.x;
    const int tid = threadIdx.x;

    if (bid < NPACKBLK) {
        // ---- pack: one site per thread ----
        const int site = bid * 256 + tid;
        unsigned pk[32];
        {
            int tmp[48];
            const int4* v = (const int4*)(a_idx + (size_t)site * 48);
            #pragma unroll
            for (int j = 0; j < 12; ++j) ((int4*)tmp)[j] = v[j];
            #pragma unroll
            for (int l = 0; l < 16; ++l)
                pk[l] = (unsigned)((tmp[l*3+2]*HW + tmp[l*3+0]*W_ + tmp[l*3+1]) << 6);
        }
        {
            int tmp[48];
            const int4* v = (const int4*)(b_idx + (size_t)site * 48);
            #pragma unroll
            for (int j = 0; j < 12; ++j) ((int4*)tmp)[j] = v[j];
            #pragma unroll
            for (int l = 0; l < 16; ++l)
                pk[16 + l] = (unsigned)((tmp[l*3+2]*HW + tmp[l*3+0]*W_ + tmp[l*3+1]) << 6);
        }
        uint4* dst = (uint4*)(offs + (size_t)site * 32);
        #pragma unroll
        for (int j = 0; j < 8; ++j)
            dst[j] = make_uint4(pk[4*j], pk[4*j+1], pk[4*j+2], pk[4*j+3]);
    } else if (bid < NPACKBLK + NTRANBLK) {
        // ---- transpose 64(b) x 64(o) tile: x[b][obase+o] -> xt[obase+o][b] ----
        __shared__ float tile[64][65];
        const int obase = (bid - NPACKBLK) * 64;
        const int c0 = tid & 63;          // o within tile (read) / b (write)
        const int r0 = tid >> 6;          // 0..3
        #pragma unroll
        for (int r = 0; r < 16; ++r) {
            const int b = r * 4 + r0;
            tile[b][c0] = x[(size_t)b * CHW + obase + c0];
        }
        __syncthreads();
        #pragma unroll
        for (int r = 0; r < 16; ++r) {
            const int o = r * 4 + r0;
            xt[(size_t)(obase + o) * 64 + c0] = tile[c0][o];
        }
    } else {
        // ---- coefs ----
        const int t = (bid - NPACKBLK - NTRANBLK) * 256 + tid;
        if (t >= K_ * 31) return;
        const int k = t / 31;
        const int node = t - k * 31;
        int d, l;
        if      (node < 16) { d = 0; l = node; }
        else if (node < 24) { d = 1; l = node - 16; }
        else if (node < 28) { d = 2; l = node - 24; }
        else if (node < 30) { d = 3; l = node - 28; }
        else                { d = 4; l = 0; }
        const float* W;
        switch (d) {
            case 0: W = w0; break;
            case 1: W = w1; break;
            case 2: W = w2; break;
            case 3: W = w3; break;
            default: W = w4; break;
        }
        const float* row = W + ((size_t)l * K_ + k) * 16;
        float m = row[0];
        #pragma unroll
        for (int o = 1; o < 16; ++o) m = fmaxf(m, row[o]);
        float e[16];
        float Z = 0.0f;
        #pragma unroll
        for (int o = 0; o < 16; ++o) { e[o] = expf(row[o] - m); Z += e[o]; }
        const float inv = 1.0f / Z;
        float c0 = 0.f, c1 = 0.f, c2 = 0.f, c3 = 0.f;
        #pragma unroll
        for (int o = 0; o < 16; ++o) {
            c0 += e[o] * COEF_[o][0];
            c1 += e[o] * COEF_[o][1];
            c2 += e[o] * COEF_[o][2];
            c3 += e[o] * COEF_[o][3];
        }
        cws[t] = make_float4(c0 * inv, c1 * inv, c2 * inv, c3 * inv);
    }
}

// binary op: y = c0 + c1*a + c2*b + c3*a*b  ==  fma(b, fma(c3,a,c2), fma(c1,a,c0))
__device__ __forceinline__ float binop(float a, float b, float4 c) {
    return fmaf(b, fmaf(c.w, a, c.z), fmaf(c.y, a, c.x));
}

// ---- kernel 2: main. Block = 64 consecutive sites, lane = batch image. ----
__global__ __launch_bounds__(256) void logicconv_main(
    const float* __restrict__ xt,       // [CHW][64]
    const unsigned* __restrict__ offs,  // [SITES][32]
    const float4* __restrict__ cws,
    float* __restrict__ out)            // [B][SITES]
{
    __shared__ float yt[64][65];

    const int tid  = threadIdx.x;
    const int lane = tid & 63;                                    // batch b
    const int w    = __builtin_amdgcn_readfirstlane(tid >> 6);    // wave 0..3
    const int s0   = blockIdx.x * 64;                             // first site

    #pragma unroll 4
    for (int i = 0; i < 16; ++i) {
        const int pl   = i * 4 + w;             // site-local 0..63 (uniform)
        const int site = s0 + pl;
        const int k    = site / P_;             // uniform (scalar div)
        const unsigned* __restrict__ ob = offs + (size_t)site * 32;
        const float4*   __restrict__ cw = cws + (size_t)k * 31;

        float va[16], vb[16];
        #pragma unroll
        for (int j = 0; j < 16; ++j) {
            va[j] = xt[(size_t)ob[j]      + lane];
            vb[j] = xt[(size_t)ob[16 + j] + lane];
        }
        float y[16];
        #pragma unroll
        for (int l = 0; l < 16; ++l) y[l] = binop(va[l], vb[l], cw[l]);
        #pragma unroll
        for (int l = 0; l < 8; ++l)  y[l] = binop(y[2*l], y[2*l+1], cw[16 + l]);
        #pragma unroll
        for (int l = 0; l < 4; ++l)  y[l] = binop(y[2*l], y[2*l+1], cw[24 + l]);
        #pragma unroll
        for (int l = 0; l < 2; ++l)  y[l] = binop(y[2*l], y[2*l+1], cw[28 + l]);
        yt[pl][lane] = binop(y[0], y[1], cw[30]);
    }
    __syncthreads();

    // coalesced write-out: lane -> consecutive site, row b = 4r + w
    #pragma unroll
    for (int r = 0; r < 16; ++r) {
        const int b = r * 4 + w;
        out[(size_t)b * SITES + s0 + lane] = yt[lane][b];
    }
}

extern "C" void kernel_launch(void* const* d_in, const int* in_sizes, int n_in,
                              void* d_out, int out_size, void* d_ws, size_t ws_size,
                              hipStream_t stream) {
    const float* x     = (const float*)d_in[0];
    const float* w0    = (const float*)d_in[1];
    const float* w1    = (const float*)d_in[2];
    const float* w2    = (const float*)d_in[3];
    const float* w3    = (const float*)d_in[4];
    const float* w4    = (const float*)d_in[5];
    const int*   a_idx = (const int*)d_in[6];
    const int*   b_idx = (const int*)d_in[7];
    float* out = (float*)d_out;

    // ws layout: xt (8 MB) | offs (6.4 MB) | cws (32 KB)
    float*    xt   = (float*)d_ws;
    unsigned* offs = (unsigned*)((char*)d_ws + (size_t)CHW * 64 * 4);
    float4*   cws  = (float4*)((char*)offs + (size_t)SITES * 32 * 4);

    prep_kernel<<<NPACKBLK + NTRANBLK + NCOEFBLK, 256, 0, stream>>>(
        x, a_idx, b_idx, w0, w1, w2, w3, w4, xt, offs, cws);

    logicconv_main<<<SITES / 64, 256, 0, stream>>>(xt, offs, cws, out);
}

// Round 8
// 34.631 us; speedup vs baseline: 1.5243x; 1.5243x over previous
//
#include <hip/hip_runtime.h>
#include <hip/hip_bf16.h>

// LogicConv3d: B=64, C=32, H=32, W=32, K=64, P=784, S=16 gathers/side.
// R8: dual-image threads + analytic offsets.
//  - offset(k,p,l) = base(k,l) + disp(p), disp(p) = (p + 4*(p/28)) elems.
//    bases are wave-uniform -> s_load from an 8KB table; offs array, its
//    205MB of reads, and per-gather u16 unpack all eliminated.
//  - each thread computes (k,p) for TWO images: even image from LDS
//    (ds_read), odd image from global (same voffset reg, saddr form,
//    coalesced; ~512KB/XCD footprint -> L2-safe). Gathers split across
//    ds + VMEM pipes; addressing VALU halved. VALU (tree) is the wall.
//  - coefs via s_load (SMEM pipe) as in R6.

#define B_  64
#define C_  32
#define H_  32
#define W_  32
#define K_  64
#define P_  784
#define CHW (C_*H_*W_)      // 32768 floats = 128 KB
#define HW  (H_*W_)         // 1024
#define SITES (K_*P_)       // 50176

__constant__ float COEF_[16][4] = {
    {0, 0, 0, 0}, {0, 0, 0, 1}, {0, 1, 0, -1}, {0, 1, 0, 0},
    {0, 0, 1, -1}, {0, 0, 1, 0}, {0, 1, 1, -2}, {0, 1, 1, -1},
    {1, -1, -1, 1}, {1, -1, -1, 2}, {1, 0, -1, 0}, {1, 0, -1, 1},
    {1, -1, 0, 0}, {1, -1, 0, 1}, {1, 0, 0, -1}, {1, 0, 0, 0}
};

// ---- kernel 1: tiny prep = bases (jobs 0..2047) + coefs (2048..4031) ----
// base[k][j] (j<16: A side l=j, j>=16: B side l=j-16), BYTE offsets.
// Uses a_idx/b_idx at p=0 where hg=wg=0: triple = (h_off, w_off, c_off).
__global__ __launch_bounds__(256) void prep_kernel(
    const int* __restrict__ a_idx, const int* __restrict__ b_idx,
    const float* __restrict__ w0, const float* __restrict__ w1,
    const float* __restrict__ w2, const float* __restrict__ w3,
    const float* __restrict__ w4,
    int* __restrict__ baseAB,        // [K_][32]
    float4* __restrict__ cws)        // [K_*31]
{
    const int t = blockIdx.x * 256 + threadIdx.x;
    if (t < K_ * 32) {
        const int k = t >> 5;
        const int j = t & 31;
        const int* src = (j < 16) ? a_idx : b_idx;
        const int l = j & 15;
        const size_t ii = ((size_t)k * P_ * 16 + l) * 3;   // site (k, p=0, l)
        const int h = src[ii + 0];
        const int w = src[ii + 1];
        const int c = src[ii + 2];
        baseAB[t] = (c << 12) + (h << 7) + (w << 2);       // bytes
    } else if (t < K_ * 32 + K_ * 31) {
        const int tt = t - K_ * 32;
        const int k = tt / 31;
        const int node = tt - k * 31;
        int d, l;
        if      (node < 16) { d = 0; l = node; }
        else if (node < 24) { d = 1; l = node - 16; }
        else if (node < 28) { d = 2; l = node - 24; }
        else if (node < 30) { d = 3; l = node - 28; }
        else                { d = 4; l = 0; }
        const float* W;
        switch (d) {
            case 0: W = w0; break;
            case 1: W = w1; break;
            case 2: W = w2; break;
            case 3: W = w3; break;
            default: W = w4; break;
        }
        const float* row = W + ((size_t)l * K_ + k) * 16;
        float m = row[0];
        #pragma unroll
        for (int o = 1; o < 16; ++o) m = fmaxf(m, row[o]);
        float e[16];
        float Z = 0.0f;
        #pragma unroll
        for (int o = 0; o < 16; ++o) { e[o] = expf(row[o] - m); Z += e[o]; }
        const float inv = 1.0f / Z;
        float c0 = 0.f, c1 = 0.f, c2 = 0.f, c3 = 0.f;
        #pragma unroll
        for (int o = 0; o < 16; ++o) {
            c0 += e[o] * COEF_[o][0];
            c1 += e[o] * COEF_[o][1];
            c2 += e[o] * COEF_[o][2];
            c3 += e[o] * COEF_[o][3];
        }
        cws[tt] = make_float4(c0 * inv, c1 * inv, c2 * inv, c3 * inv);
    }
}

// ---- kernel 2: main. Block = (image-pair bp, kgroup kg). 1024 thr, 1/CU. ----
__global__ __launch_bounds__(1024, 4) void logicconv_main(
    const float* __restrict__ x,
    const int* __restrict__ baseAB,
    const float4* __restrict__ cws,
    float* __restrict__ out)
{
    __shared__ float simg[CHW];   // even image, 128 KB

    const int tid = threadIdx.x;
    const int bp  = blockIdx.x >> 3;   // 0..31 image pair
    const int kg  = blockIdx.x & 7;    // 0..7  (fastest: 8 blocks share pair)
    const int b0  = bp * 2;

    // stage EVEN image into LDS (coalesced float4)
    {
        const float4* xi = (const float4*)(x + (size_t)b0 * CHW);
        float4* si = (float4*)simg;
        #pragma unroll
        for (int j = 0; j < CHW / 4 / 1024; ++j)   // 8
            si[tid + j * 1024] = xi[tid + j * 1024];
    }
    __syncthreads();

    // 8 groups of 128 threads; group owns one k (wave-uniform)
    const int g    = __builtin_amdgcn_readfirstlane(tid >> 7);
    const int lane = tid & 127;
    const int k    = kg * 8 + g;

    const int*    __restrict__ bA = baseAB + k * 32;          // s_load
    const float4* __restrict__ cw = cws + (size_t)k * 31;     // s_load
    const char*   sb = (const char*)simg;
    const char*   x1 = (const char*)(x + (size_t)(b0 + 1) * CHW);  // odd image
    float* __restrict__ o0 = out + ((size_t)b0 * K_ + k) * P_;
    float* __restrict__ o1 = out + ((size_t)(b0 + 1) * K_ + k) * P_;

    for (int s = 0; s < 7; ++s) {
        const int p = s * 128 + lane;
        if (p < P_) {
            const unsigned dp   = (unsigned)p / 28u;
            const unsigned disp = ((unsigned)p << 2) + (dp << 4);  // bytes

            float yx[16], yy[16];
            #pragma unroll
            for (int l = 0; l < 16; ++l) {
                const unsigned ea = (unsigned)bA[l]      + disp;
                const unsigned eb = (unsigned)bA[16 + l] + disp;
                const float a0 = *(const float*)(sb + ea);   // ds_read
                const float bb0 = *(const float*)(sb + eb);  // ds_read
                const float a1 = *(const float*)(x1 + ea);   // global saddr
                const float bb1 = *(const float*)(x1 + eb);  // global saddr
                const float4 c = cw[l];
                yx[l] = fmaf(c.w, a0 * bb0, fmaf(c.z, bb0, fmaf(c.y, a0, c.x)));
                yy[l] = fmaf(c.w, a1 * bb1, fmaf(c.z, bb1, fmaf(c.y, a1, c.x)));
            }
            #pragma unroll
            for (int l = 0; l < 8; ++l) {
                const float4 c = cw[16 + l];
                const float ax = yx[2*l], bx = yx[2*l+1];
                const float ay = yy[2*l], by = yy[2*l+1];
                yx[l] = fmaf(c.w, ax * bx, fmaf(c.z, bx, fmaf(c.y, ax, c.x)));
                yy[l] = fmaf(c.w, ay * by, fmaf(c.z, by, fmaf(c.y, ay, c.x)));
            }
            #pragma unroll
            for (int l = 0; l < 4; ++l) {
                const float4 c = cw[24 + l];
                const float ax = yx[2*l], bx = yx[2*l+1];
                const float ay = yy[2*l], by = yy[2*l+1];
                yx[l] = fmaf(c.w, ax * bx, fmaf(c.z, bx, fmaf(c.y, ax, c.x)));
                yy[l] = fmaf(c.w, ay * by, fmaf(c.z, by, fmaf(c.y, ay, c.x)));
            }
            #pragma unroll
            for (int l = 0; l < 2; ++l) {
                const float4 c = cw[28 + l];
                const float ax = yx[2*l], bx = yx[2*l+1];
                const float ay = yy[2*l], by = yy[2*l+1];
                yx[l] = fmaf(c.w, ax * bx, fmaf(c.z, bx, fmaf(c.y, ax, c.x)));
                yy[l] = fmaf(c.w, ay * by, fmaf(c.z, by, fmaf(c.y, ay, c.x)));
            }
            {
                const float4 c = cw[30];
                o0[p] = fmaf(c.w, yx[0] * yx[1], fmaf(c.z, yx[1], fmaf(c.y, yx[0], c.x)));
                o1[p] = fmaf(c.w, yy[0] * yy[1], fmaf(c.z, yy[1], fmaf(c.y, yy[0], c.x)));
            }
        }
    }
}

extern "C" void kernel_launch(void* const* d_in, const int* in_sizes, int n_in,
                              void* d_out, int out_size, void* d_ws, size_t ws_size,
                              hipStream_t stream) {
    const float* x     = (const float*)d_in[0];
    const float* w0    = (const float*)d_in[1];
    const float* w1    = (const float*)d_in[2];
    const float* w2    = (const float*)d_in[3];
    const float* w3    = (const float*)d_in[4];
    const float* w4    = (const float*)d_in[5];
    const int*   a_idx = (const int*)d_in[6];
    const int*   b_idx = (const int*)d_in[7];
    float* out = (float*)d_out;

    // ws layout: baseAB (8 KB) | cws (32 KB)
    int*    baseAB = (int*)d_ws;
    float4* cws    = (float4*)((char*)d_ws + (size_t)K_ * 32 * 4);

    prep_kernel<<<16, 256, 0, stream>>>(a_idx, b_idx, w0, w1, w2, w3, w4,
                                        baseAB, cws);

    logicconv_main<<<32 * 8, 1024, 0, stream>>>(x, baseAB, cws, out);
}

// Round 9
// 32.313 us; speedup vs baseline: 1.6337x; 1.0717x over previous
//
#include <hip/hip_runtime.h>
#include <hip/hip_bf16.h>

// LogicConv3d: B=64, C=32, H=32, W=32, K=64, P=784, S=16 gathers/side.
// R9: R8 (dual-image, analytic offsets) + p-pair vectorization.
//  - Rows are 28 wide (even) => pair (2t,2t+1) always same row => its two
//    offsets differ by 4B. One address serves 2 p x 2 images (4 outputs):
//    LDS pair -> ds_read2_b32 (merged), global pair -> 2 dwords same voffset,
//    stores -> float2. ~2x fewer ds/addr/loop instructions per output.
//  - binop in 3-fma form (93 FLOP/elem instead of 124).
//  - grid: bid = kg*32 + bp (kg SLOW). With round-robin block->XCD dispatch,
//    each XCD sees bp % 8 == const -> 4 odd images (512KB) per XCD L2.

#define B_  64
#define C_  32
#define H_  32
#define W_  32
#define K_  64
#define P_  784
#define CHW (C_*H_*W_)      // 32768 floats = 128 KB
#define HW  (H_*W_)         // 1024
#define SITES (K_*P_)       // 50176
#define NPAIR (P_/2)        // 392

__constant__ float COEF_[16][4] = {
    {0, 0, 0, 0}, {0, 0, 0, 1}, {0, 1, 0, -1}, {0, 1, 0, 0},
    {0, 0, 1, -1}, {0, 0, 1, 0}, {0, 1, 1, -2}, {0, 1, 1, -1},
    {1, -1, -1, 1}, {1, -1, -1, 2}, {1, 0, -1, 0}, {1, 0, -1, 1},
    {1, -1, 0, 0}, {1, -1, 0, 1}, {1, 0, 0, -1}, {1, 0, 0, 0}
};

// ---- kernel 1: tiny prep = bases (0..2047) + coefs (2048..4031) ----
__global__ __launch_bounds__(256) void prep_kernel(
    const int* __restrict__ a_idx, const int* __restrict__ b_idx,
    const float* __restrict__ w0, const float* __restrict__ w1,
    const float* __restrict__ w2, const float* __restrict__ w3,
    const float* __restrict__ w4,
    int* __restrict__ baseAB,        // [K_][32] byte offsets
    float4* __restrict__ cws)        // [K_*31]
{
    const int t = blockIdx.x * 256 + threadIdx.x;
    if (t < K_ * 32) {
        const int k = t >> 5;
        const int j = t & 31;
        const int* src = (j < 16) ? a_idx : b_idx;
        const int l = j & 15;
        const size_t ii = ((size_t)k * P_ * 16 + l) * 3;   // site (k, p=0, l)
        const int h = src[ii + 0];
        const int w = src[ii + 1];
        const int c = src[ii + 2];
        baseAB[t] = (c << 12) + (h << 7) + (w << 2);       // bytes
    } else if (t < K_ * 32 + K_ * 31) {
        const int tt = t - K_ * 32;
        const int k = tt / 31;
        const int node = tt - k * 31;
        int d, l;
        if      (node < 16) { d = 0; l = node; }
        else if (node < 24) { d = 1; l = node - 16; }
        else if (node < 28) { d = 2; l = node - 24; }
        else if (node < 30) { d = 3; l = node - 28; }
        else                { d = 4; l = 0; }
        const float* W;
        switch (d) {
            case 0: W = w0; break;
            case 1: W = w1; break;
            case 2: W = w2; break;
            case 3: W = w3; break;
            default: W = w4; break;
        }
        const float* row = W + ((size_t)l * K_ + k) * 16;
        float m = row[0];
        #pragma unroll
        for (int o = 1; o < 16; ++o) m = fmaxf(m, row[o]);
        float e[16];
        float Z = 0.0f;
        #pragma unroll
        for (int o = 0; o < 16; ++o) { e[o] = expf(row[o] - m); Z += e[o]; }
        const float inv = 1.0f / Z;
        float c0 = 0.f, c1 = 0.f, c2 = 0.f, c3 = 0.f;
        #pragma unroll
        for (int o = 0; o < 16; ++o) {
            c0 += e[o] * COEF_[o][0];
            c1 += e[o] * COEF_[o][1];
            c2 += e[o] * COEF_[o][2];
            c3 += e[o] * COEF_[o][3];
        }
        cws[tt] = make_float4(c0 * inv, c1 * inv, c2 * inv, c3 * inv);
    }
}

// y = c0 + c1*a + c2*b + c3*a*b == fma(b, fma(c3,a,c2), fma(c1,a,c0))
__device__ __forceinline__ float binop(float a, float b, float4 c) {
    return fmaf(b, fmaf(c.w, a, c.z), fmaf(c.y, a, c.x));
}

// ---- kernel 2: main. bid = kg*32 + bp. 1024 thr, 1 block/CU. ----
__global__ __launch_bounds__(1024, 4) void logicconv_main(
    const float* __restrict__ x,
    const int* __restrict__ baseAB,
    const float4* __restrict__ cws,
    float* __restrict__ out)
{
    __shared__ float simg[CHW];   // even image, 128 KB

    const int tid = threadIdx.x;
    const int kg  = blockIdx.x >> 5;   // 0..7  (slow)
    const int bp  = blockIdx.x & 31;   // 0..31 (fast -> XCD = bp%8 fixed/XCD)
    const int b0  = bp * 2;

    // stage EVEN image into LDS (coalesced float4)
    {
        const float4* xi = (const float4*)(x + (size_t)b0 * CHW);
        float4* si = (float4*)simg;
        #pragma unroll
        for (int j = 0; j < 8; ++j)
            si[tid + j * 1024] = xi[tid + j * 1024];
    }
    __syncthreads();

    // 8 groups of 128 threads; group owns one k (wave-uniform)
    const int g    = __builtin_amdgcn_readfirstlane(tid >> 7);
    const int lane = tid & 127;
    const int k    = kg * 8 + g;

    const int*    __restrict__ bA = baseAB + k * 32;          // s_load
    const float4* __restrict__ cw = cws + (size_t)k * 31;     // s_load
    const char*   sb = (const char*)simg;
    const char*   x1 = (const char*)(x + (size_t)(b0 + 1) * CHW);  // odd image
    float* __restrict__ o0 = out + ((size_t)b0 * K_ + k) * P_;
    float* __restrict__ o1 = o0 + (size_t)K_ * P_;

    for (int s = 0; s < 4; ++s) {
        const int t = s * 128 + lane;          // pair index
        if (t >= NPAIR) break;                 // only s==3 partial (8 lanes)
        const unsigned row  = (unsigned)t / 14u;            // p0/28, p0=2t
        const unsigned disp = 8u * (unsigned)t + 16u * row; // byte disp

        float2 ye[16], yo[16];
        #pragma unroll
        for (int l = 0; l < 16; ++l) {
            const unsigned ea = (unsigned)bA[l]      + disp;
            const unsigned eb = (unsigned)bA[16 + l] + disp;
            const float ae0 = *(const float*)(sb + ea);
            const float ae1 = *(const float*)(sb + ea + 4);   // ds_read2_b32
            const float be0 = *(const float*)(sb + eb);
            const float be1 = *(const float*)(sb + eb + 4);
            const float ao0 = *(const float*)(x1 + ea);
            const float ao1 = *(const float*)(x1 + ea + 4);
            const float bo0 = *(const float*)(x1 + eb);
            const float bo1 = *(const float*)(x1 + eb + 4);
            const float4 c = cw[l];
            ye[l].x = binop(ae0, be0, c);  ye[l].y = binop(ae1, be1, c);
            yo[l].x = binop(ao0, bo0, c);  yo[l].y = binop(ao1, bo1, c);
        }
        #pragma unroll
        for (int l = 0; l < 8; ++l) {
            const float4 c = cw[16 + l];
            ye[l].x = binop(ye[2*l].x, ye[2*l+1].x, c);
            ye[l].y = binop(ye[2*l].y, ye[2*l+1].y, c);
            yo[l].x = binop(yo[2*l].x, yo[2*l+1].x, c);
            yo[l].y = binop(yo[2*l].y, yo[2*l+1].y, c);
        }
        #pragma unroll
        for (int l = 0; l < 4; ++l) {
            const float4 c = cw[24 + l];
            ye[l].x = binop(ye[2*l].x, ye[2*l+1].x, c);
            ye[l].y = binop(ye[2*l].y, ye[2*l+1].y, c);
            yo[l].x = binop(yo[2*l].x, yo[2*l+1].x, c);
            yo[l].y = binop(yo[2*l].y, yo[2*l+1].y, c);
        }
        #pragma unroll
        for (int l = 0; l < 2; ++l) {
            const float4 c = cw[28 + l];
            ye[l].x = binop(ye[2*l].x, ye[2*l+1].x, c);
            ye[l].y = binop(ye[2*l].y, ye[2*l+1].y, c);
            yo[l].x = binop(yo[2*l].x, yo[2*l+1].x, c);
            yo[l].y = binop(yo[2*l].y, yo[2*l+1].y, c);
        }
        {
            const float4 c = cw[30];
            float2 re, ro;
            re.x = binop(ye[0].x, ye[1].x, c);
            re.y = binop(ye[0].y, ye[1].y, c);
            ro.x = binop(yo[0].x, yo[1].x, c);
            ro.y = binop(yo[0].y, yo[1].y, c);
            *(float2*)(o0 + 2 * t) = re;   // 8B-aligned: index even
            *(float2*)(o1 + 2 * t) = ro;
        }
    }
}

extern "C" void kernel_launch(void* const* d_in, const int* in_sizes, int n_in,
                              void* d_out, int out_size, void* d_ws, size_t ws_size,
                              hipStream_t stream) {
    const float* x     = (const float*)d_in[0];
    const float* w0    = (const float*)d_in[1];
    const float* w1    = (const float*)d_in[2];
    const float* w2    = (const float*)d_in[3];
    const float* w3    = (const float*)d_in[4];
    const float* w4    = (const float*)d_in[5];
    const int*   a_idx = (const int*)d_in[6];
    const int*   b_idx = (const int*)d_in[7];
    float* out = (float*)d_out;

    // ws layout: baseAB (8 KB) | cws (32 KB)
    int*    baseAB = (int*)d_ws;
    float4* cws    = (float4*)((char*)d_ws + (size_t)K_ * 32 * 4);

    prep_kernel<<<16, 256, 0, stream>>>(a_idx, b_idx, w0, w1, w2, w3, w4,
                                        baseAB, cws);

    logicconv_main<<<256, 1024, 0, stream>>>(x, baseAB, cws, out);
}

// Round 10
// 30.155 us; speedup vs baseline: 1.7506x; 1.0716x over previous
//
#include <hip/hip_runtime.h>
#include <hip/hip_bf16.h>

// LogicConv3d: B=64, C=32, H=32, W=32, K=64, P=784, S=16 gathers/side.
// R10: R9 (dual-image, analytic offsets, p-pair vectorization) with the
// load/use structure fixed for latency hiding:
//  - R9 interleaved load->binop per leaf l: each odd-image global load's
//    ~200-600cyc latency was exposed after only ~12 VALU ops, and 4
//    waves/SIMD can't cover that. R8->R9 counter deltas showed instruction
//    halving gained little -> latency-bound, not throughput-bound.
//  - R10: per s-iter, two half-batches of 8 leaves; per half ALL 32 odd
//    global loads issue first, then all 16 ds_read2 pairs, then layer-0.
//    ~48 outstanding loads amortize one latency window; scheduler can
//    overlap half1 loads with half0 compute. Peak ~112 VGPR < 128.

#define B_  64
#define C_  32
#define H_  32
#define W_  32
#define K_  64
#define P_  784
#define CHW (C_*H_*W_)      // 32768 floats = 128 KB
#define HW  (H_*W_)         // 1024
#define SITES (K_*P_)       // 50176
#define NPAIR (P_/2)        // 392

__constant__ float COEF_[16][4] = {
    {0, 0, 0, 0}, {0, 0, 0, 1}, {0, 1, 0, -1}, {0, 1, 0, 0},
    {0, 0, 1, -1}, {0, 0, 1, 0}, {0, 1, 1, -2}, {0, 1, 1, -1},
    {1, -1, -1, 1}, {1, -1, -1, 2}, {1, 0, -1, 0}, {1, 0, -1, 1},
    {1, -1, 0, 0}, {1, -1, 0, 1}, {1, 0, 0, -1}, {1, 0, 0, 0}
};

// ---- kernel 1: tiny prep = bases (0..2047) + coefs (2048..4031) ----
__global__ __launch_bounds__(256) void prep_kernel(
    const int* __restrict__ a_idx, const int* __restrict__ b_idx,
    const float* __restrict__ w0, const float* __restrict__ w1,
    const float* __restrict__ w2, const float* __restrict__ w3,
    const float* __restrict__ w4,
    int* __restrict__ baseAB,        // [K_][32] byte offsets
    float4* __restrict__ cws)        // [K_*31]
{
    const int t = blockIdx.x * 256 + threadIdx.x;
    if (t < K_ * 32) {
        const int k = t >> 5;
        const int j = t & 31;
        const int* src = (j < 16) ? a_idx : b_idx;
        const int l = j & 15;
        const size_t ii = ((size_t)k * P_ * 16 + l) * 3;   // site (k, p=0, l)
        const int h = src[ii + 0];
        const int w = src[ii + 1];
        const int c = src[ii + 2];
        baseAB[t] = (c << 12) + (h << 7) + (w << 2);       // bytes
    } else if (t < K_ * 32 + K_ * 31) {
        const int tt = t - K_ * 32;
        const int k = tt / 31;
        const int node = tt - k * 31;
        int d, l;
        if      (node < 16) { d = 0; l = node; }
        else if (node < 24) { d = 1; l = node - 16; }
        else if (node < 28) { d = 2; l = node - 24; }
        else if (node < 30) { d = 3; l = node - 28; }
        else                { d = 4; l = 0; }
        const float* W;
        switch (d) {
            case 0: W = w0; break;
            case 1: W = w1; break;
            case 2: W = w2; break;
            case 3: W = w3; break;
            default: W = w4; break;
        }
        const float* row = W + ((size_t)l * K_ + k) * 16;
        float m = row[0];
        #pragma unroll
        for (int o = 1; o < 16; ++o) m = fmaxf(m, row[o]);
        float e[16];
        float Z = 0.0f;
        #pragma unroll
        for (int o = 0; o < 16; ++o) { e[o] = expf(row[o] - m); Z += e[o]; }
        const float inv = 1.0f / Z;
        float c0 = 0.f, c1 = 0.f, c2 = 0.f, c3 = 0.f;
        #pragma unroll
        for (int o = 0; o < 16; ++o) {
            c0 += e[o] * COEF_[o][0];
            c1 += e[o] * COEF_[o][1];
            c2 += e[o] * COEF_[o][2];
            c3 += e[o] * COEF_[o][3];
        }
        cws[tt] = make_float4(c0 * inv, c1 * inv, c2 * inv, c3 * inv);
    }
}

// y = c0 + c1*a + c2*b + c3*a*b == fma(b, fma(c3,a,c2), fma(c1,a,c0))
__device__ __forceinline__ float binop(float a, float b, float4 c) {
    return fmaf(b, fmaf(c.w, a, c.z), fmaf(c.y, a, c.x));
}

// ---- kernel 2: main. bid = kg*32 + bp. 1024 thr, 1 block/CU. ----
__global__ __launch_bounds__(1024, 4) void logicconv_main(
    const float* __restrict__ x,
    const int* __restrict__ baseAB,
    const float4* __restrict__ cws,
    float* __restrict__ out)
{
    __shared__ float simg[CHW];   // even image, 128 KB

    const int tid = threadIdx.x;
    const int kg  = blockIdx.x >> 5;   // 0..7  (slow)
    const int bp  = blockIdx.x & 31;   // 0..31 (fast)
    const int b0  = bp * 2;

    // stage EVEN image into LDS (coalesced float4)
    {
        const float4* xi = (const float4*)(x + (size_t)b0 * CHW);
        float4* si = (float4*)simg;
        #pragma unroll
        for (int j = 0; j < 8; ++j)
            si[tid + j * 1024] = xi[tid + j * 1024];
    }
    __syncthreads();

    // 8 groups of 128 threads; group owns one k (wave-uniform)
    const int g    = __builtin_amdgcn_readfirstlane(tid >> 7);
    const int lane = tid & 127;
    const int k    = kg * 8 + g;

    const int*    __restrict__ bA = baseAB + k * 32;          // s_load
    const float4* __restrict__ cw = cws + (size_t)k * 31;     // s_load
    const char*   sb = (const char*)simg;
    const char*   x1 = (const char*)(x + (size_t)(b0 + 1) * CHW);  // odd image
    float* __restrict__ o0 = out + ((size_t)b0 * K_ + k) * P_;
    float* __restrict__ o1 = o0 + (size_t)K_ * P_;

    for (int s = 0; s < 4; ++s) {
        const int t = s * 128 + lane;          // pair index
        if (t < NPAIR) {
            const unsigned row  = (unsigned)t / 14u;            // p0/28, p0=2t
            const unsigned disp = 8u * (unsigned)t + 16u * row; // byte disp

            float2 ye[16], yo[16];
            #pragma unroll
            for (int h = 0; h < 2; ++h) {
                unsigned ea[8], eb[8];
                #pragma unroll
                for (int j = 0; j < 8; ++j) {
                    ea[j] = (unsigned)bA[h*8 + j]      + disp;
                    eb[j] = (unsigned)bA[16 + h*8 + j] + disp;
                }
                // 1) issue ALL odd-image global loads for this half
                float od[32];
                #pragma unroll
                for (int j = 0; j < 8; ++j) {
                    od[4*j+0] = *(const float*)(x1 + ea[j]);
                    od[4*j+1] = *(const float*)(x1 + ea[j] + 4);
                    od[4*j+2] = *(const float*)(x1 + eb[j]);
                    od[4*j+3] = *(const float*)(x1 + eb[j] + 4);
                }
                // 2) issue ALL even-image LDS pair reads (ds_read2_b32)
                float ev[32];
                #pragma unroll
                for (int j = 0; j < 8; ++j) {
                    ev[4*j+0] = *(const float*)(sb + ea[j]);
                    ev[4*j+1] = *(const float*)(sb + ea[j] + 4);
                    ev[4*j+2] = *(const float*)(sb + eb[j]);
                    ev[4*j+3] = *(const float*)(sb + eb[j] + 4);
                }
                // 3) layer-0 for this half
                #pragma unroll
                for (int j = 0; j < 8; ++j) {
                    const int l = h*8 + j;
                    const float4 c = cw[l];
                    ye[l].x = binop(ev[4*j+0], ev[4*j+2], c);
                    ye[l].y = binop(ev[4*j+1], ev[4*j+3], c);
                    yo[l].x = binop(od[4*j+0], od[4*j+2], c);
                    yo[l].y = binop(od[4*j+1], od[4*j+3], c);
                }
            }
            #pragma unroll
            for (int l = 0; l < 8; ++l) {
                const float4 c = cw[16 + l];
                ye[l].x = binop(ye[2*l].x, ye[2*l+1].x, c);
                ye[l].y = binop(ye[2*l].y, ye[2*l+1].y, c);
                yo[l].x = binop(yo[2*l].x, yo[2*l+1].x, c);
                yo[l].y = binop(yo[2*l].y, yo[2*l+1].y, c);
            }
            #pragma unroll
            for (int l = 0; l < 4; ++l) {
                const float4 c = cw[24 + l];
                ye[l].x = binop(ye[2*l].x, ye[2*l+1].x, c);
                ye[l].y = binop(ye[2*l].y, ye[2*l+1].y, c);
                yo[l].x = binop(yo[2*l].x, yo[2*l+1].x, c);
                yo[l].y = binop(yo[2*l].y, yo[2*l+1].y, c);
            }
            #pragma unroll
            for (int l = 0; l < 2; ++l) {
                const float4 c = cw[28 + l];
                ye[l].x = binop(ye[2*l].x, ye[2*l+1].x, c);
                ye[l].y = binop(ye[2*l].y, ye[2*l+1].y, c);
                yo[l].x = binop(yo[2*l].x, yo[2*l+1].x, c);
                yo[l].y = binop(yo[2*l].y, yo[2*l+1].y, c);
            }
            {
                const float4 c = cw[30];
                float2 re, ro;
                re.x = binop(ye[0].x, ye[1].x, c);
                re.y = binop(ye[0].y, ye[1].y, c);
                ro.x = binop(yo[0].x, yo[1].x, c);
                ro.y = binop(yo[0].y, yo[1].y, c);
                *(float2*)(o0 + 2 * t) = re;   // 8B-aligned (even index)
                *(float2*)(o1 + 2 * t) = ro;
            }
        }
    }
}

extern "C" void kernel_launch(void* const* d_in, const int* in_sizes, int n_in,
                              void* d_out, int out_size, void* d_ws, size_t ws_size,
                              hipStream_t stream) {
    const float* x     = (const float*)d_in[0];
    const float* w0    = (const float*)d_in[1];
    const float* w1    = (const float*)d_in[2];
    const float* w2    = (const float*)d_in[3];
    const float* w3    = (const float*)d_in[4];
    const float* w4    = (const float*)d_in[5];
    const int*   a_idx = (const int*)d_in[6];
    const int*   b_idx = (const int*)d_in[7];
    float* out = (float*)d_out;

    // ws layout: baseAB (8 KB) | cws (32 KB)
    int*    baseAB = (int*)d_ws;
    float4* cws    = (float4*)((char*)d_ws + (size_t)K_ * 32 * 4);

    prep_kernel<<<16, 256, 0, stream>>>(a_idx, b_idx, w0, w1, w2, w3, w4,
                                        baseAB, cws);

    logicconv_main<<<256, 1024, 0, stream>>>(x, baseAB, cws, out);
}